// Round 7
// baseline (178.407 us; speedup 1.0000x reference)
//
#include <hip/hip_runtime.h>
#include <hip/hip_bf16.h>
#include <math.h>

#define BTOT 32768

typedef float f32x4 __attribute__((ext_vector_type(4)));
typedef __bf16 v8bf __attribute__((ext_vector_type(8)));

// Scratch in device globals (graph-capture safe).
__device__ float g_x[BTOT * 128];                       // 16.8 MB intermediate
__device__ float g_M[2 * 8 * 16 * 64];                  // folded AT^T @ pw_w1
__device__ float g_b1p[2 * 8 * 64];                     // pw_b1 + colsum(pw_w1)
__device__ __align__(16) unsigned short g_wf[1792 * 128]; // [E;T] bf16, B-fragment-swizzled
__device__ float g_beff[128];                           // ctx_b + emb_b@Wc1 + tri_b@Wc2
__device__ float g_wr[128];                             // ctx_w row 96 (rm column)

__device__ __forceinline__ float gelu_f(float v) {
    return 0.5f * v * (1.0f + erff(v * 0.70710678118654752f));
}

__device__ __forceinline__ unsigned short f2bf_rne(float x) {
    unsigned u = __float_as_uint(x);
    u += 0x7fffu + ((u >> 16) & 1u);
    return (unsigned short)(u >> 16);
}

#define GLOAD16(gp, lp)                                                        \
    __builtin_amdgcn_global_load_lds(                                          \
        (const __attribute__((address_space(1))) void*)(gp),                   \
        (__attribute__((address_space(3))) void*)(lp), 16, 0, 0)

// ---------------------------------------------------------------------------
// k_pre: per (l,p): slerp anchors -> fold AT^T @ pw_w1 into g_M, g_b1p.
// ---------------------------------------------------------------------------
__global__ __launch_bounds__(64) void k_pre(const float* __restrict__ home,
                                            const float* __restrict__ anchors,
                                            const float* __restrict__ pw_w1,
                                            const float* __restrict__ pw_b1) {
    __shared__ float s_AT[48 * 16];
    const int lp = blockIdx.x;   // 0..15  (l*8+p)
    const int tid = threadIdx.x; // 0..63
    if (tid < 48) {
        const int t = tid >> 4, a = tid & 15;
        const float* hp = home + (lp * 16 + a) * 16;
        const float* cp = anchors + (lp * 16 + a) * 16;
        float h[16], c[16], nh = 0.f, nc = 0.f;
#pragma unroll
        for (int i = 0; i < 16; ++i) {
            h[i] = hp[i]; nh = fmaf(h[i], h[i], nh);
            c[i] = cp[i]; nc = fmaf(c[i], c[i], nc);
        }
        const float ih = 1.f / fmaxf(sqrtf(nh), 1e-12f);
        const float ic = 1.f / fmaxf(sqrtf(nc), 1e-12f);
        float cw = 0.f;
#pragma unroll
        for (int i = 0; i < 16; ++i) { h[i] *= ih; c[i] *= ic; cw = fmaf(h[i], c[i], cw); }
        cw = fminf(fmaxf(cw, -1.f + 1e-7f), 1.f - 1e-7f);
        const float om = acosf(cw);
        const float so = fmaxf(sinf(om), 1e-7f);
        const float tt = (float)t * (1.f / 3.f);
        const float s1 = sinf((1.f - tt) * om), s2 = sinf(tt * om);
        float v[16], nv = 0.f;
#pragma unroll
        for (int i = 0; i < 16; ++i) { v[i] = (s1 * h[i] + s2 * c[i]) / so; nv = fmaf(v[i], v[i], nv); }
        const float iv = 1.f / fmaxf(sqrtf(nv), 1e-12f);
#pragma unroll
        for (int i = 0; i < 16; ++i) s_AT[tid * 16 + i] = v[i] * iv;
    }
    __syncthreads();
    const int h = tid;
    const float* w1 = pw_w1 + lp * 48 * 64;
    float b = pw_b1[lp * 64 + h];
    float m[16];
#pragma unroll
    for (int d = 0; d < 16; ++d) m[d] = 0.f;
    for (int j = 0; j < 48; ++j) {
        const float w = w1[j * 64 + h];
        b += w;
#pragma unroll
        for (int d = 0; d < 16; ++d) m[d] = fmaf(s_AT[j * 16 + d], w, m[d]);
    }
    g_b1p[lp * 64 + h] = b;
#pragma unroll
    for (int d = 0; d < 16; ++d) g_M[(lp * 16 + d) * 64 + h] = m[d];
}

// ---------------------------------------------------------------------------
// k_fold: W = [emb_w@Wc1 ; tri_w@Wc2] (1792x128) -> bf16, swizzled into MFMA
// B-fragment-linear order. Block 56 also computes b_eff and wr.
// ---------------------------------------------------------------------------
__global__ __launch_bounds__(256) void k_fold(const float* __restrict__ emb_w,
                                              const float* __restrict__ tri_w,
                                              const float* __restrict__ ctx_w,
                                              const float* __restrict__ ctx_b,
                                              const float* __restrict__ emb_b,
                                              const float* __restrict__ tri_b) {
    if (blockIdx.x == 56) {
        const int n = threadIdx.x;
        if (n < 128) {
            float b = ctx_b[n];
            for (int c = 0; c < 64; ++c) b = fmaf(emb_b[c], ctx_w[c * 128 + n], b);
            for (int c = 0; c < 32; ++c) b = fmaf(tri_b[c], ctx_w[(64 + c) * 128 + n], b);
            g_beff[n] = b;
            g_wr[n] = ctx_w[96 * 128 + n];
        }
        return;
    }
    __shared__ float sctx[97 * 128];
    for (int q = threadIdx.x; q < 3104; q += 256)
        *(float4*)&sctx[q * 4] = *(const float4*)&ctx_w[q * 4];
    __syncthreads();
    const int kt = blockIdx.x;
    const int kr = threadIdx.x >> 3;       // 0..31 row within k-tile
    const int n0 = (threadIdx.x & 7) * 16; // 16 output cols per thread
    const int k = kt * 32 + kr;
    float acc[16];
#pragma unroll
    for (int j = 0; j < 16; ++j) acc[j] = 0.f;
    if (k < 768) {
        const float* wrow = emb_w + k * 64;
        for (int c = 0; c < 64; ++c) {
            const float a = wrow[c];
            const float* cx = &sctx[c * 128 + n0];
#pragma unroll
            for (int j = 0; j < 16; ++j) acc[j] = fmaf(a, cx[j], acc[j]);
        }
    } else {
        const float* wrow = tri_w + (k - 768) * 32;
        for (int c = 0; c < 32; ++c) {
            const float a = wrow[c];
            const float* cx = &sctx[(64 + c) * 128 + n0];
#pragma unroll
            for (int j = 0; j < 16; ++j) acc[j] = fmaf(a, cx[j], acc[j]);
        }
    }
    const int nt = threadIdx.x & 7;
    const int lanehi = (kr >> 3) << 4;
    const int j8 = kr & 7;
#pragma unroll
    for (int q = 0; q < 16; ++q) {
        const int lane = lanehi | q;
        g_wf[((kt * 8 + nt) * 64 + lane) * 8 + j8] = f2bf_rne(acc[q]);
    }
}

// ---------------------------------------------------------------------------
// k_front_mfma v3: A direct-to-reg (no LDS; rows are wave-private so LDS-A
// bought nothing), B triple-buffered in LDS (3x16KB), counted vmcnt(16) +
// raw s_barrier so 2 iterations of loads (16) stay in flight across every
// barrier. 64 rows/block (4 waves x 16 rows), K-tile 64, 28 tiles.
// ---------------------------------------------------------------------------
__global__ __launch_bounds__(256) void k_front_mfma(const float* __restrict__ emb,
                                                    const float* __restrict__ tri,
                                                    const float* __restrict__ rm) {
    __shared__ __align__(16) char lds[49152];   // B0 | B1 | B2 (16KB each)
    const int tid = threadIdx.x;
    const int lane = tid & 63, w = tid >> 6;
    const int row0 = blockIdx.x * 64;
    const int arow = lane & 15, kgrp = lane >> 4;

    f32x4 acc[8];
#pragma unroll
    for (int nt = 0; nt < 8; ++nt) {
        f32x4 z = {0.f, 0.f, 0.f, 0.f};
        acc[nt] = z;
    }

    // per-lane A row pointers (col base kgrp*8)
    const float* embp = emb + (size_t)(row0 + w * 16 + arow) * 768 + kgrp * 8;
    const float* trip = tri + (size_t)(row0 + w * 16 + arow) * 1024 + kgrp * 8;

    float4 A0[4], A1[4], A2[4];   // 3 static A slots (16 f32 each)

#define STAGE_B(kk, BUF) {                                                     \
        const int k2_ = (kk) < 27 ? (kk) : 27;                                 \
        const char* gB_ = (const char*)g_wf + (size_t)k2_ * 16384              \
                          + w * 4096 + lane * 16;                              \
        char* Bb_ = lds + (BUF) * 16384 + w * 4096;          /* uniform */     \
        _Pragma("unroll")                                                      \
        for (int i = 0; i < 4; ++i) GLOAD16(gB_ + i * 1024, Bb_ + i * 1024);   \
    }

#define ALOAD(kk, S) {                                                         \
        const int k2_ = (kk) < 27 ? (kk) : 27;                                 \
        const float* ab_ = (k2_ < 12) ? (embp + k2_ * 64) : (trip + (k2_ - 12) * 64); \
        S[0] = *(const float4*)(ab_);                                          \
        S[1] = *(const float4*)(ab_ + 4);                                      \
        S[2] = *(const float4*)(ab_ + 32);                                     \
        S[3] = *(const float4*)(ab_ + 36);                                     \
    }

#define COMPUTE(BUF, S) {                                                      \
        const char* Br_ = lds + (BUF) * 16384 + lane * 16;                     \
        _Pragma("unroll")                                                      \
        for (int h = 0; h < 2; ++h) {                                          \
            const float4 f0_ = S[h * 2], f1_ = S[h * 2 + 1];                   \
            v8bf a_;                                                           \
            a_[0] = (__bf16)f0_.x; a_[1] = (__bf16)f0_.y;                      \
            a_[2] = (__bf16)f0_.z; a_[3] = (__bf16)f0_.w;                      \
            a_[4] = (__bf16)f1_.x; a_[5] = (__bf16)f1_.y;                      \
            a_[6] = (__bf16)f1_.z; a_[7] = (__bf16)f1_.w;                      \
            const char* bp_ = Br_ + h * 8192;                                  \
            _Pragma("unroll")                                                  \
            for (int nt = 0; nt < 8; ++nt) {                                   \
                const v8bf b_ = *(const v8bf*)(bp_ + nt * 1024);               \
                acc[nt] = __builtin_amdgcn_mfma_f32_16x16x32_bf16(a_, b_, acc[nt], 0, 0, 0); \
            }                                                                  \
        }                                                                      \
    }

    // BODY(k): stage k+2 into buf I2 / slot S2, wait for k's 8 loads
    // (leaving 16 in flight), barrier, compute k, barrier.
#define BODY(kk, I0, I2, S0, S2) {                                             \
        STAGE_B((kk) + 2, I2);                                                 \
        ALOAD((kk) + 2, S2);                                                   \
        asm volatile("s_waitcnt vmcnt(16)" ::: "memory");                      \
        __builtin_amdgcn_s_barrier();                                          \
        COMPUTE(I0, S0);                                                       \
        __builtin_amdgcn_s_barrier();                                          \
    }

    // prologue: tiles 0 and 1 in flight (16 loads outstanding)
    STAGE_B(0, 0); ALOAD(0, A0);
    STAGE_B(1, 1); ALOAD(1, A1);

    for (int t = 0; t < 9; ++t) {
        const int k = t * 3;
        BODY(k,     0, 2, A0, A2);
        BODY(k + 1, 1, 0, A1, A0);
        BODY(k + 2, 2, 1, A2, A1);
    }
    BODY(27, 0, 2, A0, A2);
    asm volatile("s_waitcnt vmcnt(0)" ::: "memory");   // drain leftovers
#undef STAGE_B
#undef ALOAD
#undef COMPUTE
#undef BODY

    // epilogue: + rm*wr + b_eff, write g_x.  C/D: col=lane&15, row=(lane>>4)*4+reg.
    const int rowb = row0 + w * 16 + kgrp * 4;
    const f32x4 rv = *(const f32x4*)&rm[rowb];
#pragma unroll
    for (int nt = 0; nt < 8; ++nt) {
        const int col = nt * 16 + arow;
        const float be = g_beff[col];
        const float wv = g_wr[col];
#pragma unroll
        for (int rr = 0; rr < 4; ++rr) {
            g_x[(size_t)(rowb + rr) * 128 + col] = acc[nt][rr] + rv[rr] * wv + be;
        }
    }
}

// ---------------------------------------------------------------------------
// k_relay (R=2 row-paired): unchanged from round 6.
// ---------------------------------------------------------------------------
__global__ __launch_bounds__(256) void k_relay(
    const float* __restrict__ pw_w2, const float* __restrict__ pw_b2,
    const float* __restrict__ pwn_g, const float* __restrict__ pwn_b,
    const float* __restrict__ gates, const float* __restrict__ norm_g,
    const float* __restrict__ norm_b, const float* __restrict__ head_w1,
    const float* __restrict__ head_b1, const float* __restrict__ head_w2,
    const float* __restrict__ head_b2, const float* __restrict__ stats_bias,
    float* __restrict__ out) {
    __shared__ __align__(16) float s_M[8 * 1028];
    __shared__ __align__(16) float s_w2[8 * 1028];
    __shared__ __align__(16) float s_b1p[8 * 68];
    __shared__ __align__(16) float s_hw1[8 * 132];
    __shared__ float s_hb1[64], s_hw2[64], s_hcb[8];
    __shared__ float s_mc[64 * 8];
    const int tid = threadIdx.x;
    const int pr = tid >> 3, p = tid & 7;
    const int rowA = blockIdx.x * 64 + pr * 2;   // rowB = rowA + 1

    {   // stage head weights (256 float4 == 1024 floats exactly)
        const int e = tid * 4, pp = e >> 7, rem = e & 127;
        *(float4*)&s_hw1[pp * 132 + rem] = *(const float4*)&head_w1[e];
    }
    if (tid < 64) { s_hb1[tid] = head_b1[tid]; s_hw2[tid] = head_w2[tid]; }
    if (tid < 8) s_hcb[tid] = head_b2[tid] + stats_bias[tid];

    float xA[16], xB[16];
    {
        const float* xp = g_x + (size_t)rowA * 128 + p * 16;
#pragma unroll
        for (int i = 0; i < 4; ++i) {
            *(float4*)&xA[i * 4] = *(const float4*)&xp[i * 4];
            *(float4*)&xB[i * 4] = *(const float4*)&xp[128 + i * 4];
        }
    }

    for (int l = 0; l < 2; ++l) {
        if (l) __syncthreads();
        for (int q = tid; q < 2048; q += 256) {
            const int e = q * 4, pp = e >> 10, rem = e & 1023;
            *(float4*)&s_M[pp * 1028 + rem] = *(const float4*)&g_M[l * 8192 + e];
            *(float4*)&s_w2[pp * 1028 + rem] = *(const float4*)&pw_w2[l * 8192 + e];
        }
        if (tid < 128) {
            const int e = tid * 4, pp = e >> 6, rem = e & 63;
            *(float4*)&s_b1p[pp * 68 + rem] = *(const float4*)&g_b1p[l * 512 + e];
        }
        __syncthreads();

        // LayerNorm over the 128-dim rows (8 lanes of same pair cooperate)
        float sA = 0.f, qA = 0.f, sB = 0.f, qB = 0.f;
#pragma unroll
        for (int i = 0; i < 16; ++i) {
            sA += xA[i]; qA = fmaf(xA[i], xA[i], qA);
            sB += xB[i]; qB = fmaf(xB[i], xB[i], qB);
        }
#pragma unroll
        for (int m = 1; m < 8; m <<= 1) {
            sA += __shfl_xor(sA, m, 64); qA += __shfl_xor(qA, m, 64);
            sB += __shfl_xor(sB, m, 64); qB += __shfl_xor(qB, m, 64);
        }
        const float muA = sA * (1.f / 128.f);
        const float rsA = rsqrtf(fmaxf(qA * (1.f / 128.f) - muA * muA, 0.f) + 1e-5f);
        const float muB = sB * (1.f / 128.f);
        const float rsB = rsqrtf(fmaxf(qB * (1.f / 128.f) - muB * muB, 0.f) + 1e-5f);
        float paA[16], paB[16], nA = 0.f, nB = 0.f;
#pragma unroll
        for (int i = 0; i < 16; ++i) {
            const float gg = norm_g[l * 128 + p * 16 + i];
            const float bb = norm_b[l * 128 + p * 16 + i];
            const float vA = (xA[i] - muA) * rsA * gg + bb;
            const float vB = (xB[i] - muB) * rsB * gg + bb;
            paA[i] = vA; nA = fmaf(vA, vA, nA);
            paB[i] = vB; nB = fmaf(vB, vB, nB);
        }
        const float invA = 1.f / fmaxf(sqrtf(nA), 1e-12f);
        const float invB = 1.f / fmaxf(sqrtf(nB), 1e-12f);

        float pwA[16], pwB[16];
#pragma unroll
        for (int i = 0; i < 16; ++i) {
            const float b2 = pw_b2[(l * 8 + p) * 16 + i];
            pwA[i] = b2; pwB[i] = b2;
        }
        const float* Mp = &s_M[p * 1028];
        const float* W2p = &s_w2[p * 1028];
        const float* Bp = &s_b1p[p * 68];
        for (int h4 = 0; h4 < 16; ++h4) {
            float bq[4];
            *(float4*)bq = *(const float4*)&Bp[h4 * 4];
            float aA[4] = {0.f, 0.f, 0.f, 0.f};
            float aB[4] = {0.f, 0.f, 0.f, 0.f};
#pragma unroll
            for (int d = 0; d < 16; ++d) {
                float m4[4];
                *(float4*)m4 = *(const float4*)&Mp[d * 64 + h4 * 4];
#pragma unroll
                for (int j = 0; j < 4; ++j) {
                    aA[j] = fmaf(paA[d], m4[j], aA[j]);
                    aB[j] = fmaf(paB[d], m4[j], aB[j]);
                }
            }
#pragma unroll
            for (int j = 0; j < 4; ++j) {
                const float gA = gelu_f(bq[j] - invA * aA[j]);
                const float gB = gelu_f(bq[j] - invB * aB[j]);
                float w[16];
#pragma unroll
                for (int u = 0; u < 4; ++u)
                    *(float4*)&w[u * 4] = *(const float4*)&W2p[(h4 * 4 + j) * 16 + u * 4];
#pragma unroll
                for (int u = 0; u < 16; ++u) {
                    pwA[u] = fmaf(gA, w[u], pwA[u]);
                    pwB[u] = fmaf(gB, w[u], pwB[u]);
                }
            }
        }
        // LN16 on pw, gate, residual combine (both rows)
        float s2A = 0.f, q2A = 0.f, s2B = 0.f, q2B = 0.f;
#pragma unroll
        for (int i = 0; i < 16; ++i) {
            s2A += pwA[i]; q2A = fmaf(pwA[i], pwA[i], q2A);
            s2B += pwB[i]; q2B = fmaf(pwB[i], pwB[i], q2B);
        }
        const float mu2A = s2A * (1.f / 16.f);
        const float rs2A = rsqrtf(fmaxf(q2A * (1.f / 16.f) - mu2A * mu2A, 0.f) + 1e-5f);
        const float mu2B = s2B * (1.f / 16.f);
        const float rs2B = rsqrtf(fmaxf(q2B * (1.f / 16.f) - mu2B * mu2B, 0.f) + 1e-5f);
        const float gate = 1.f / (1.f + expf(-gates[l * 8 + p]));
#pragma unroll
        for (int i = 0; i < 16; ++i) {
            const float pg = pwn_g[l * 16 + i], pb = pwn_b[l * 16 + i];
            const float vA = (pwA[i] - mu2A) * rs2A * pg + pb;
            const float vB = (pwB[i] - mu2B) * rs2B * pg + pb;
            xA[i] = xA[i] + gate * vA + (1.f - gate) * paA[i];
            xB[i] = xB[i] + gate * vB + (1.f - gate) * paB[i];
        }
    }

    // head: per (row-pair, patch), head weights amortized over both rows
    float accmA = s_hcb[p], accmB = accmA;
#pragma unroll
    for (int j = 0; j < 8; ++j) {
        float aA = s_hb1[p * 8 + j], aB = aA;
#pragma unroll
        for (int d = 0; d < 16; ++d) {
            const float w = s_hw1[p * 132 + d * 8 + j];
            aA = fmaf(xA[d], w, aA);
            aB = fmaf(xB[d], w, aB);
        }
        const float w2h = s_hw2[p * 8 + j];
        accmA = fmaf(gelu_f(aA), w2h, accmA);
        accmB = fmaf(gelu_f(aB), w2h, accmB);
    }
    const float mcA = 0.1f + 4.9f / (1.f + expf(-accmA));
    const float mcB = 0.1f + 4.9f / (1.f + expf(-accmB));
    s_mc[(pr * 2) * 8 + p] = mcA;
    s_mc[(pr * 2 + 1) * 8 + p] = mcB;
    out[(size_t)33554432 + (size_t)rowA * 8 + p] = mcA;
    out[(size_t)33554432 + (size_t)(rowA + 1) * 8 + p] = mcB;
    __syncthreads();

    // mag = repeat(mc, 128): cooperative fully-coalesced float4 writes
    const size_t base = (size_t)blockIdx.x * 64 * 1024;
#pragma unroll
    for (int it = 0; it < 64; ++it) {
        const int idx = it * 256 + tid;
        const int rr = idx >> 8, c4 = idx & 255;
        const float v = s_mc[rr * 8 + (c4 >> 5)];
        const float4 vv = make_float4(v, v, v, v);
        *(float4*)&out[base + rr * 1024 + c4 * 4] = vv;
    }
}

// ---------------------------------------------------------------------------
extern "C" void kernel_launch(void* const* d_in, const int* in_sizes, int n_in,
                              void* d_out, int out_size, void* d_ws, size_t ws_size,
                              hipStream_t stream) {
    (void)in_sizes; (void)n_in; (void)d_ws; (void)ws_size; (void)out_size;
    const float* emb = (const float*)d_in[0];
    const float* tria = (const float*)d_in[1];
    const float* rm = (const float*)d_in[2];
    const float* emb_w = (const float*)d_in[3];
    const float* emb_b = (const float*)d_in[4];
    const float* tri_w = (const float*)d_in[5];
    const float* tri_b = (const float*)d_in[6];
    const float* ctx_w = (const float*)d_in[7];
    const float* ctx_b = (const float*)d_in[8];
    const float* home = (const float*)d_in[9];
    const float* anch = (const float*)d_in[10];
    const float* pw_w1 = (const float*)d_in[11];
    const float* pw_b1 = (const float*)d_in[12];
    const float* pw_w2 = (const float*)d_in[13];
    const float* pw_b2 = (const float*)d_in[14];
    const float* pwn_g = (const float*)d_in[15];
    const float* pwn_b = (const float*)d_in[16];
    const float* gates = (const float*)d_in[17];
    const float* norm_g = (const float*)d_in[18];
    const float* norm_b = (const float*)d_in[19];
    const float* hw1 = (const float*)d_in[20];
    const float* hb1 = (const float*)d_in[21];
    const float* hw2 = (const float*)d_in[22];
    const float* hb2 = (const float*)d_in[23];
    const float* sb = (const float*)d_in[24];
    float* out = (float*)d_out;

    k_pre<<<16, 64, 0, stream>>>(home, anch, pw_w1, pw_b1);
    k_fold<<<57, 256, 0, stream>>>(emb_w, tri_w, ctx_w, ctx_b, emb_b, tri_b);
    k_front_mfma<<<512, 256, 0, stream>>>(emb, tria, rm);
    k_relay<<<512, 256, 0, stream>>>(pw_w2, pw_b2, pwn_g, pwn_b, gates, norm_g, norm_b,
                                     hw1, hb1, hw2, hb2, sb, out);
}

// Round 8
// 161.019 us; speedup vs baseline: 1.1080x; 1.1080x over previous
//
#include <hip/hip_runtime.h>
#include <hip/hip_bf16.h>
#include <math.h>

#define BTOT 32768

typedef float f32x4 __attribute__((ext_vector_type(4)));
typedef __bf16 v8bf __attribute__((ext_vector_type(8)));

// Scratch in device globals (graph-capture safe).
__device__ float g_x[BTOT * 128];                       // 16.8 MB intermediate
__device__ float g_M[2 * 8 * 16 * 64];                  // folded AT^T @ pw_w1
__device__ float g_b1p[2 * 8 * 64];                     // pw_b1 + colsum(pw_w1)
__device__ __align__(16) unsigned short g_wf[1792 * 128]; // [E;T] bf16, B-fragment-swizzled
__device__ float g_beff[128];                           // ctx_b + emb_b@Wc1 + tri_b@Wc2
__device__ float g_wr[128];                             // ctx_w row 96 (rm column)

__device__ __forceinline__ float fast_rcp(float x) {
#if __has_builtin(__builtin_amdgcn_rcpf)
    return __builtin_amdgcn_rcpf(x);
#else
    return 1.f / x;
#endif
}

// tanh-form gelu: x*sigmoid(1.5957691x + 0.0713548x^3); |err| ~1e-3, and the
// relay path is gated x0.047 -> negligible vs 0.1 threshold.
__device__ __forceinline__ float gelu_f(float v) {
    const float p = v * fmaf(v * v, 0.0713548162f, 1.59576912f);
    return v * fast_rcp(1.f + __expf(-p));
}

__device__ __forceinline__ float fast_sigmoid(float v) {
    return fast_rcp(1.f + __expf(-v));
}

__device__ __forceinline__ unsigned short f2bf_rne(float x) {
    unsigned u = __float_as_uint(x);
    u += 0x7fffu + ((u >> 16) & 1u);
    return (unsigned short)(u >> 16);
}

#define GLOAD16(gp, lp)                                                        \
    __builtin_amdgcn_global_load_lds(                                          \
        (const __attribute__((address_space(1))) void*)(gp),                   \
        (__attribute__((address_space(3))) void*)(lp), 16, 0, 0)

// ---------------------------------------------------------------------------
// k_pre: per (l,p): slerp anchors -> fold AT^T @ pw_w1 into g_M, g_b1p.
// ---------------------------------------------------------------------------
__global__ __launch_bounds__(64) void k_pre(const float* __restrict__ home,
                                            const float* __restrict__ anchors,
                                            const float* __restrict__ pw_w1,
                                            const float* __restrict__ pw_b1) {
    __shared__ float s_AT[48 * 16];
    const int lp = blockIdx.x;   // 0..15  (l*8+p)
    const int tid = threadIdx.x; // 0..63
    if (tid < 48) {
        const int t = tid >> 4, a = tid & 15;
        const float* hp = home + (lp * 16 + a) * 16;
        const float* cp = anchors + (lp * 16 + a) * 16;
        float h[16], c[16], nh = 0.f, nc = 0.f;
#pragma unroll
        for (int i = 0; i < 16; ++i) {
            h[i] = hp[i]; nh = fmaf(h[i], h[i], nh);
            c[i] = cp[i]; nc = fmaf(c[i], c[i], nc);
        }
        const float ih = 1.f / fmaxf(sqrtf(nh), 1e-12f);
        const float ic = 1.f / fmaxf(sqrtf(nc), 1e-12f);
        float cw = 0.f;
#pragma unroll
        for (int i = 0; i < 16; ++i) { h[i] *= ih; c[i] *= ic; cw = fmaf(h[i], c[i], cw); }
        cw = fminf(fmaxf(cw, -1.f + 1e-7f), 1.f - 1e-7f);
        const float om = acosf(cw);
        const float so = fmaxf(sinf(om), 1e-7f);
        const float tt = (float)t * (1.f / 3.f);
        const float s1 = sinf((1.f - tt) * om), s2 = sinf(tt * om);
        float v[16], nv = 0.f;
#pragma unroll
        for (int i = 0; i < 16; ++i) { v[i] = (s1 * h[i] + s2 * c[i]) / so; nv = fmaf(v[i], v[i], nv); }
        const float iv = 1.f / fmaxf(sqrtf(nv), 1e-12f);
#pragma unroll
        for (int i = 0; i < 16; ++i) s_AT[tid * 16 + i] = v[i] * iv;
    }
    __syncthreads();
    const int h = tid;
    const float* w1 = pw_w1 + lp * 48 * 64;
    float b = pw_b1[lp * 64 + h];
    float m[16];
#pragma unroll
    for (int d = 0; d < 16; ++d) m[d] = 0.f;
    for (int j = 0; j < 48; ++j) {
        const float w = w1[j * 64 + h];
        b += w;
#pragma unroll
        for (int d = 0; d < 16; ++d) m[d] = fmaf(s_AT[j * 16 + d], w, m[d]);
    }
    g_b1p[lp * 64 + h] = b;
#pragma unroll
    for (int d = 0; d < 16; ++d) g_M[(lp * 16 + d) * 64 + h] = m[d];
}

// ---------------------------------------------------------------------------
// k_fold: W = [emb_w@Wc1 ; tri_w@Wc2] (1792x128) -> bf16, swizzled into MFMA
// B-fragment-linear order. Block 56 also computes b_eff and wr.
// ---------------------------------------------------------------------------
__global__ __launch_bounds__(256) void k_fold(const float* __restrict__ emb_w,
                                              const float* __restrict__ tri_w,
                                              const float* __restrict__ ctx_w,
                                              const float* __restrict__ ctx_b,
                                              const float* __restrict__ emb_b,
                                              const float* __restrict__ tri_b) {
    if (blockIdx.x == 56) {
        const int n = threadIdx.x;
        if (n < 128) {
            float b = ctx_b[n];
            for (int c = 0; c < 64; ++c) b = fmaf(emb_b[c], ctx_w[c * 128 + n], b);
            for (int c = 0; c < 32; ++c) b = fmaf(tri_b[c], ctx_w[(64 + c) * 128 + n], b);
            g_beff[n] = b;
            g_wr[n] = ctx_w[96 * 128 + n];
        }
        return;
    }
    __shared__ float sctx[97 * 128];
    for (int q = threadIdx.x; q < 3104; q += 256)
        *(float4*)&sctx[q * 4] = *(const float4*)&ctx_w[q * 4];
    __syncthreads();
    const int kt = blockIdx.x;
    const int kr = threadIdx.x >> 3;       // 0..31 row within k-tile
    const int n0 = (threadIdx.x & 7) * 16; // 16 output cols per thread
    const int k = kt * 32 + kr;
    float acc[16];
#pragma unroll
    for (int j = 0; j < 16; ++j) acc[j] = 0.f;
    if (k < 768) {
        const float* wrow = emb_w + k * 64;
        for (int c = 0; c < 64; ++c) {
            const float a = wrow[c];
            const float* cx = &sctx[c * 128 + n0];
#pragma unroll
            for (int j = 0; j < 16; ++j) acc[j] = fmaf(a, cx[j], acc[j]);
        }
    } else {
        const float* wrow = tri_w + (k - 768) * 32;
        for (int c = 0; c < 32; ++c) {
            const float a = wrow[c];
            const float* cx = &sctx[(64 + c) * 128 + n0];
#pragma unroll
            for (int j = 0; j < 16; ++j) acc[j] = fmaf(a, cx[j], acc[j]);
        }
    }
    const int nt = threadIdx.x & 7;
    const int lanehi = (kr >> 3) << 4;
    const int j8 = kr & 7;
#pragma unroll
    for (int q = 0; q < 16; ++q) {
        const int lane = lanehi | q;
        g_wf[((kt * 8 + nt) * 64 + lane) * 8 + j8] = f2bf_rne(acc[q]);
    }
}

// ---------------------------------------------------------------------------
// k_front_mfma v4 (BK=128): doubles per-row read contiguity (512B/row/tile)
// to attack the DRAM page-granularity wall; halves barrier count (14 tiles).
// B dbuf 2x32KB LDS via global_load_lds; A in 2 register slots (32 VGPR ea).
// Counted vmcnt(16) keeps one full tile (8 A + 8 B loads) in flight across
// every barrier. 64 rows/block (4 waves x 16 rows), 512 blocks.
// ---------------------------------------------------------------------------
__global__ __launch_bounds__(256) void k_front_mfma(const float* __restrict__ emb,
                                                    const float* __restrict__ tri,
                                                    const float* __restrict__ rm) {
    __shared__ __align__(16) char lds[65536];   // B0 | B1 (32KB each)
    const int tid = threadIdx.x;
    const int lane = tid & 63, w = tid >> 6;
    const int row0 = blockIdx.x * 64;
    const int arow = lane & 15, kgrp = lane >> 4;

    f32x4 acc[8];
#pragma unroll
    for (int nt = 0; nt < 8; ++nt) {
        f32x4 z = {0.f, 0.f, 0.f, 0.f};
        acc[nt] = z;
    }

    // per-lane A row pointers (col base kgrp*8); tiles 0..5 emb, 6..13 tri
    const float* embp = emb + (size_t)(row0 + w * 16 + arow) * 768 + kgrp * 8;
    const float* trip = tri + (size_t)(row0 + w * 16 + arow) * 1024 + kgrp * 8;

    float4 A0[8], A1[8];   // 2 static A slots (32 f32 each = one BK=128 slab)

#define ALOAD(kk, S) {                                                         \
        const int k2_ = (kk) < 13 ? (kk) : 13;                                 \
        const float* ab_ = (k2_ < 6) ? (embp + k2_ * 128)                      \
                                     : (trip + (k2_ - 6) * 128);               \
        _Pragma("unroll")                                                      \
        for (int s = 0; s < 4; ++s) {                                          \
            S[s * 2]     = *(const float4*)(ab_ + s * 32);                     \
            S[s * 2 + 1] = *(const float4*)(ab_ + s * 32 + 4);                 \
        }                                                                      \
    }

#define STAGE_B(kk, BUF) {                                                     \
        const int k2_ = (kk) < 13 ? (kk) : 13;                                 \
        const char* gB_ = (const char*)g_wf + (size_t)k2_ * 32768              \
                          + w * 8192 + lane * 16;                              \
        char* Bb_ = lds + (BUF) * 32768 + w * 8192;          /* uniform */     \
        _Pragma("unroll")                                                      \
        for (int i = 0; i < 8; ++i) GLOAD16(gB_ + i * 1024, Bb_ + i * 1024);   \
    }

#define COMPUTE(BUF, S) {                                                      \
        const char* Br_ = lds + (BUF) * 32768 + lane * 16;                     \
        _Pragma("unroll")                                                      \
        for (int s = 0; s < 4; ++s) {                                          \
            const float4 f0_ = S[s * 2], f1_ = S[s * 2 + 1];                   \
            v8bf a_;                                                           \
            a_[0] = (__bf16)f0_.x; a_[1] = (__bf16)f0_.y;                      \
            a_[2] = (__bf16)f0_.z; a_[3] = (__bf16)f0_.w;                      \
            a_[4] = (__bf16)f1_.x; a_[5] = (__bf16)f1_.y;                      \
            a_[6] = (__bf16)f1_.z; a_[7] = (__bf16)f1_.w;                      \
            const char* bp_ = Br_ + s * 8192;                                  \
            _Pragma("unroll")                                                  \
            for (int nt = 0; nt < 8; ++nt) {                                   \
                const v8bf b_ = *(const v8bf*)(bp_ + nt * 1024);               \
                acc[nt] = __builtin_amdgcn_mfma_f32_16x16x32_bf16(a_, b_, acc[nt], 0, 0, 0); \
            }                                                                  \
        }                                                                      \
    }

    // BODY(t): issue A(t+1)+B(t+1) (16 VMEM), wait for tile t's 16 (leaving
    // the 16 just-issued in flight), barrier, compute t, barrier.
#define BODY(kk, BUFC, BUFN, SC, SN) {                                         \
        ALOAD((kk) + 1, SN);                                                   \
        STAGE_B((kk) + 1, BUFN);                                               \
        asm volatile("s_waitcnt vmcnt(16)" ::: "memory");                      \
        __builtin_amdgcn_s_barrier();                                          \
        COMPUTE(BUFC, SC);                                                     \
        __builtin_amdgcn_s_barrier();                                          \
    }

    ALOAD(0, A0);
    STAGE_B(0, 0);
    for (int t = 0; t < 6; ++t) {
        BODY(2 * t,     0, 1, A0, A1);
        BODY(2 * t + 1, 1, 0, A1, A0);
    }
    BODY(12, 0, 1, A0, A1);                 // stages tile 13 into buf1
    asm volatile("s_waitcnt vmcnt(0)" ::: "memory");
    __builtin_amdgcn_s_barrier();
    COMPUTE(1, A1);                          // tile 13
#undef ALOAD
#undef STAGE_B
#undef COMPUTE
#undef BODY

    // epilogue: + rm*wr + b_eff, write g_x.  C/D: col=lane&15, row=(lane>>4)*4+reg.
    const int rowb = row0 + w * 16 + kgrp * 4;
    const f32x4 rv = *(const f32x4*)&rm[rowb];
#pragma unroll
    for (int nt = 0; nt < 8; ++nt) {
        const int col = nt * 16 + arow;
        const float be = g_beff[col];
        const float wv = g_wr[col];
#pragma unroll
        for (int rr = 0; rr < 4; ++rr) {
            g_x[(size_t)(rowb + rr) * 128 + col] = acc[nt][rr] + rv[rr] * wv + be;
        }
    }
}

// ---------------------------------------------------------------------------
// k_relay (R=2, fast-gelu): structure unchanged from round 6; erf-gelu
// replaced by tanh-form gelu (v_exp+v_rcp, ~8 ops vs ~20+), sigmoids fast.
// ---------------------------------------------------------------------------
__global__ __launch_bounds__(256) void k_relay(
    const float* __restrict__ pw_w2, const float* __restrict__ pw_b2,
    const float* __restrict__ pwn_g, const float* __restrict__ pwn_b,
    const float* __restrict__ gates, const float* __restrict__ norm_g,
    const float* __restrict__ norm_b, const float* __restrict__ head_w1,
    const float* __restrict__ head_b1, const float* __restrict__ head_w2,
    const float* __restrict__ head_b2, const float* __restrict__ stats_bias,
    float* __restrict__ out) {
    __shared__ __align__(16) float s_M[8 * 1028];
    __shared__ __align__(16) float s_w2[8 * 1028];
    __shared__ __align__(16) float s_b1p[8 * 68];
    __shared__ __align__(16) float s_hw1[8 * 132];
    __shared__ float s_hb1[64], s_hw2[64], s_hcb[8];
    __shared__ float s_mc[64 * 8];
    const int tid = threadIdx.x;
    const int pr = tid >> 3, p = tid & 7;
    const int rowA = blockIdx.x * 64 + pr * 2;   // rowB = rowA + 1

    {   // stage head weights (256 float4 == 1024 floats exactly)
        const int e = tid * 4, pp = e >> 7, rem = e & 127;
        *(float4*)&s_hw1[pp * 132 + rem] = *(const float4*)&head_w1[e];
    }
    if (tid < 64) { s_hb1[tid] = head_b1[tid]; s_hw2[tid] = head_w2[tid]; }
    if (tid < 8) s_hcb[tid] = head_b2[tid] + stats_bias[tid];

    float xA[16], xB[16];
    {
        const float* xp = g_x + (size_t)rowA * 128 + p * 16;
#pragma unroll
        for (int i = 0; i < 4; ++i) {
            *(float4*)&xA[i * 4] = *(const float4*)&xp[i * 4];
            *(float4*)&xB[i * 4] = *(const float4*)&xp[128 + i * 4];
        }
    }

    for (int l = 0; l < 2; ++l) {
        if (l) __syncthreads();
        for (int q = tid; q < 2048; q += 256) {
            const int e = q * 4, pp = e >> 10, rem = e & 1023;
            *(float4*)&s_M[pp * 1028 + rem] = *(const float4*)&g_M[l * 8192 + e];
            *(float4*)&s_w2[pp * 1028 + rem] = *(const float4*)&pw_w2[l * 8192 + e];
        }
        if (tid < 128) {
            const int e = tid * 4, pp = e >> 6, rem = e & 63;
            *(float4*)&s_b1p[pp * 68 + rem] = *(const float4*)&g_b1p[l * 512 + e];
        }
        __syncthreads();

        // LayerNorm over the 128-dim rows (8 lanes of same pair cooperate)
        float sA = 0.f, qA = 0.f, sB = 0.f, qB = 0.f;
#pragma unroll
        for (int i = 0; i < 16; ++i) {
            sA += xA[i]; qA = fmaf(xA[i], xA[i], qA);
            sB += xB[i]; qB = fmaf(xB[i], xB[i], qB);
        }
#pragma unroll
        for (int m = 1; m < 8; m <<= 1) {
            sA += __shfl_xor(sA, m, 64); qA += __shfl_xor(qA, m, 64);
            sB += __shfl_xor(sB, m, 64); qB += __shfl_xor(qB, m, 64);
        }
        const float muA = sA * (1.f / 128.f);
        const float rsA = rsqrtf(fmaxf(qA * (1.f / 128.f) - muA * muA, 0.f) + 1e-5f);
        const float muB = sB * (1.f / 128.f);
        const float rsB = rsqrtf(fmaxf(qB * (1.f / 128.f) - muB * muB, 0.f) + 1e-5f);
        float paA[16], paB[16], nA = 0.f, nB = 0.f;
#pragma unroll
        for (int i = 0; i < 16; ++i) {
            const float gg = norm_g[l * 128 + p * 16 + i];
            const float bb = norm_b[l * 128 + p * 16 + i];
            const float vA = (xA[i] - muA) * rsA * gg + bb;
            const float vB = (xB[i] - muB) * rsB * gg + bb;
            paA[i] = vA; nA = fmaf(vA, vA, nA);
            paB[i] = vB; nB = fmaf(vB, vB, nB);
        }
        const float invA = 1.f / fmaxf(sqrtf(nA), 1e-12f);
        const float invB = 1.f / fmaxf(sqrtf(nB), 1e-12f);

        float pwA[16], pwB[16];
#pragma unroll
        for (int i = 0; i < 16; ++i) {
            const float b2 = pw_b2[(l * 8 + p) * 16 + i];
            pwA[i] = b2; pwB[i] = b2;
        }
        const float* Mp = &s_M[p * 1028];
        const float* W2p = &s_w2[p * 1028];
        const float* Bp = &s_b1p[p * 68];
        for (int h4 = 0; h4 < 16; ++h4) {
            float bq[4];
            *(float4*)bq = *(const float4*)&Bp[h4 * 4];
            float aA[4] = {0.f, 0.f, 0.f, 0.f};
            float aB[4] = {0.f, 0.f, 0.f, 0.f};
#pragma unroll
            for (int d = 0; d < 16; ++d) {
                float m4[4];
                *(float4*)m4 = *(const float4*)&Mp[d * 64 + h4 * 4];
#pragma unroll
                for (int j = 0; j < 4; ++j) {
                    aA[j] = fmaf(paA[d], m4[j], aA[j]);
                    aB[j] = fmaf(paB[d], m4[j], aB[j]);
                }
            }
#pragma unroll
            for (int j = 0; j < 4; ++j) {
                const float gA = gelu_f(bq[j] - invA * aA[j]);
                const float gB = gelu_f(bq[j] - invB * aB[j]);
                float w[16];
#pragma unroll
                for (int u = 0; u < 4; ++u)
                    *(float4*)&w[u * 4] = *(const float4*)&W2p[(h4 * 4 + j) * 16 + u * 4];
#pragma unroll
                for (int u = 0; u < 16; ++u) {
                    pwA[u] = fmaf(gA, w[u], pwA[u]);
                    pwB[u] = fmaf(gB, w[u], pwB[u]);
                }
            }
        }
        // LN16 on pw, gate, residual combine (both rows)
        float s2A = 0.f, q2A = 0.f, s2B = 0.f, q2B = 0.f;
#pragma unroll
        for (int i = 0; i < 16; ++i) {
            s2A += pwA[i]; q2A = fmaf(pwA[i], pwA[i], q2A);
            s2B += pwB[i]; q2B = fmaf(pwB[i], pwB[i], q2B);
        }
        const float mu2A = s2A * (1.f / 16.f);
        const float rs2A = rsqrtf(fmaxf(q2A * (1.f / 16.f) - mu2A * mu2A, 0.f) + 1e-5f);
        const float mu2B = s2B * (1.f / 16.f);
        const float rs2B = rsqrtf(fmaxf(q2B * (1.f / 16.f) - mu2B * mu2B, 0.f) + 1e-5f);
        const float gate = fast_sigmoid(gates[l * 8 + p]);
#pragma unroll
        for (int i = 0; i < 16; ++i) {
            const float pg = pwn_g[l * 16 + i], pb = pwn_b[l * 16 + i];
            const float vA = (pwA[i] - mu2A) * rs2A * pg + pb;
            const float vB = (pwB[i] - mu2B) * rs2B * pg + pb;
            xA[i] = xA[i] + gate * vA + (1.f - gate) * paA[i];
            xB[i] = xB[i] + gate * vB + (1.f - gate) * paB[i];
        }
    }

    // head: per (row-pair, patch), head weights amortized over both rows
    float accmA = s_hcb[p], accmB = accmA;
#pragma unroll
    for (int j = 0; j < 8; ++j) {
        float aA = s_hb1[p * 8 + j], aB = aA;
#pragma unroll
        for (int d = 0; d < 16; ++d) {
            const float w = s_hw1[p * 132 + d * 8 + j];
            aA = fmaf(xA[d], w, aA);
            aB = fmaf(xB[d], w, aB);
        }
        const float w2h = s_hw2[p * 8 + j];
        accmA = fmaf(gelu_f(aA), w2h, accmA);
        accmB = fmaf(gelu_f(aB), w2h, accmB);
    }
    const float mcA = 0.1f + 4.9f * fast_sigmoid(accmA);
    const float mcB = 0.1f + 4.9f * fast_sigmoid(accmB);
    s_mc[(pr * 2) * 8 + p] = mcA;
    s_mc[(pr * 2 + 1) * 8 + p] = mcB;
    out[(size_t)33554432 + (size_t)rowA * 8 + p] = mcA;
    out[(size_t)33554432 + (size_t)(rowA + 1) * 8 + p] = mcB;
    __syncthreads();

    // mag = repeat(mc, 128): cooperative fully-coalesced float4 writes
    const size_t base = (size_t)blockIdx.x * 64 * 1024;
#pragma unroll
    for (int it = 0; it < 64; ++it) {
        const int idx = it * 256 + tid;
        const int rr = idx >> 8, c4 = idx & 255;
        const float v = s_mc[rr * 8 + (c4 >> 5)];
        const float4 vv = make_float4(v, v, v, v);
        *(float4*)&out[base + rr * 1024 + c4 * 4] = vv;
    }
}

// ---------------------------------------------------------------------------
extern "C" void kernel_launch(void* const* d_in, const int* in_sizes, int n_in,
                              void* d_out, int out_size, void* d_ws, size_t ws_size,
                              hipStream_t stream) {
    (void)in_sizes; (void)n_in; (void)d_ws; (void)ws_size; (void)out_size;
    const float* emb = (const float*)d_in[0];
    const float* tria = (const float*)d_in[1];
    const float* rm = (const float*)d_in[2];
    const float* emb_w = (const float*)d_in[3];
    const float* emb_b = (const float*)d_in[4];
    const float* tri_w = (const float*)d_in[5];
    const float* tri_b = (const float*)d_in[6];
    const float* ctx_w = (const float*)d_in[7];
    const float* ctx_b = (const float*)d_in[8];
    const float* home = (const float*)d_in[9];
    const float* anch = (const float*)d_in[10];
    const float* pw_w1 = (const float*)d_in[11];
    const float* pw_b1 = (const float*)d_in[12];
    const float* pw_w2 = (const float*)d_in[13];
    const float* pw_b2 = (const float*)d_in[14];
    const float* pwn_g = (const float*)d_in[15];
    const float* pwn_b = (const float*)d_in[16];
    const float* gates = (const float*)d_in[17];
    const float* norm_g = (const float*)d_in[18];
    const float* norm_b = (const float*)d_in[19];
    const float* hw1 = (const float*)d_in[20];
    const float* hb1 = (const float*)d_in[21];
    const float* hw2 = (const float*)d_in[22];
    const float* hb2 = (const float*)d_in[23];
    const float* sb = (const float*)d_in[24];
    float* out = (float*)d_out;

    k_pre<<<16, 64, 0, stream>>>(home, anch, pw_w1, pw_b1);
    k_fold<<<57, 256, 0, stream>>>(emb_w, tri_w, ctx_w, ctx_b, emb_b, tri_b);
    k_front_mfma<<<512, 256, 0, stream>>>(emb, tria, rm);
    k_relay<<<512, 256, 0, stream>>>(pw_w2, pw_b2, pwn_g, pwn_b, gates, norm_g, norm_b,
                                     hw1, hb1, hw2, hb2, sb, out);
}